// Round 2
// baseline (795.258 us; speedup 1.0000x reference)
//
#include <hip/hip_runtime.h>
#include <hip/hip_bf16.h>
#include <stdint.h>

// Problem constants
#define DIM 384
#define KEY_DIM 32
#define HEADS 8
#define RES 14
#define NTOK 196          // RES*RES
#define NH_KD 256
#define DD 128            // D = RATIO*KEY_DIM
#define DHF 1024          // DD*HEADS
#define H_QKV 1536
#define BATCH 256
#define QSTR 224          // row stride for qkv intermediate (padded, 16B-aligned rows)
#define EPS_BN 1e-5f
#define SCALE_QK 0.17677669529663687f  // 32^-0.5

typedef unsigned short ushort_t;
typedef __attribute__((ext_vector_type(8))) short short8;
typedef __attribute__((ext_vector_type(4))) float floatx4;

__device__ __forceinline__ ushort_t f2bf(float f) {
  union { float f; unsigned int u; } v; v.f = f;
  unsigned int u = v.u;
  unsigned int r = (u + 0x7FFFu + ((u >> 16) & 1u)) >> 16;
  return (ushort_t)r;
}
__device__ __forceinline__ float bf2f(ushort_t h) {
  union { unsigned int u; float f; } v; v.u = ((unsigned int)h) << 16;
  return v.f;
}
__device__ __forceinline__ void async_copy16(const ushort_t* g, ushort_t* l) {
  __builtin_amdgcn_global_load_lds((const __attribute__((address_space(1))) void*)g,
                                   (__attribute__((address_space(3))) void*)l, 16, 0, 0);
}

// ---------------- prep kernels ----------------
// x (cb, c, n) fp32 -> xb (cb, n, c) bf16  (transpose via LDS tile)
__global__ void k_prep_x(const float* __restrict__ x, ushort_t* __restrict__ xb) {
  __shared__ float tile[64][65];
  const int b = blockIdx.y;
  const int c0 = blockIdx.x * 64;
  const int t = threadIdx.x;
  const int tr = t >> 6;      // 0..3
  const int tc = t & 63;
  for (int n0 = 0; n0 < NTOK; n0 += 64) {
    __syncthreads();
    #pragma unroll
    for (int k = 0; k < 16; ++k) {
      int r = k * 4 + tr;
      int n = n0 + tc;
      tile[r][tc] = (n < NTOK) ? x[((size_t)b * DIM + c0 + r) * NTOK + n] : 0.f;
    }
    __syncthreads();
    #pragma unroll
    for (int k = 0; k < 16; ++k) {
      int nl = k * 4 + tr;
      int n = n0 + nl;
      if (n < NTOK) xb[((size_t)b * NTOK + n) * DIM + c0 + tc] = f2bf(tile[tc][nl]);
    }
  }
}

__global__ void k_prep_w(const float* __restrict__ qkv_w, const float* __restrict__ proj_w,
                         ushort_t* __restrict__ wqkvb, ushort_t* __restrict__ wprojb) {
  int i = blockIdx.x * 256 + threadIdx.x;
  const int nA = H_QKV * DIM;
  const int nB = DIM * DHF;
  if (i < nA) wqkvb[i] = f2bf(qkv_w[i]);
  else if (i < nA + nB) wprojb[i - nA] = f2bf(proj_w[i - nA]);
}

__global__ void k_prep_ab(const float* __restrict__ biases, const int* __restrict__ idxs,
                          float* __restrict__ abg) {
  int i = blockIdx.x * 256 + threadIdx.x;
  if (i >= HEADS * NTOK * NTOK) return;
  int h = i / (NTOK * NTOK);
  int nm = i - h * (NTOK * NTOK);
  abg[i] = biases[h * NTOK + idxs[nm]];
}

// ---------------- GEMM (m97 structure) ----------------
// C[b](Mtile x 196) = A(M x K) * B[b](196 x K)^T  + BN epilogue.
template<int KDIM, bool OUTF32>
__global__ __launch_bounds__(256, 2) void k_gemm(
    const ushort_t* __restrict__ A, const ushort_t* __restrict__ B,
    const float* __restrict__ bn_g, const float* __restrict__ bn_b,
    const float* __restrict__ bn_m, const float* __restrict__ bn_v,
    void* __restrict__ out) {
  __shared__ ushort_t sA[128 * 32];
  __shared__ ushort_t sB[128 * 32];
  const int b = blockIdx.y;
  const int ot = blockIdx.x >> 1;
  const int nt = blockIdx.x & 1;
  const int o0 = ot * 128;
  const int n0 = nt * 128;
  const int t = threadIdx.x;
  const int w = t >> 6;
  const int l = t & 63;
  const int lr = l >> 2;
  const int ls = l & 3;
  const int arow0 = w * 32 + lr;
  const int arow1 = arow0 + 16;
  const size_t aoff0 = (size_t)(o0 + arow0) * KDIM + ls * 8;
  const size_t aoff1 = (size_t)(o0 + arow1) * KDIM + ls * 8;
  int bn0 = n0 + arow0; if (bn0 > NTOK - 1) bn0 = NTOK - 1;
  int bn1 = n0 + arow1; if (bn1 > NTOK - 1) bn1 = NTOK - 1;
  const size_t boff0 = ((size_t)b * NTOK + bn0) * KDIM + ls * 8;
  const size_t boff1 = ((size_t)b * NTOK + bn1) * KDIM + ls * 8;
  ushort_t* sA_w = sA + w * 1024;
  ushort_t* sB_w = sB + w * 1024;

  floatx4 acc[4][4];
  const floatx4 zero4 = {0.f, 0.f, 0.f, 0.f};
  #pragma unroll
  for (int i = 0; i < 4; ++i)
    #pragma unroll
    for (int j = 0; j < 4; ++j) acc[i][j] = zero4;

  const int wr = (w >> 1) * 64;
  const int wc = (w & 1) * 64;
  const int quad = l >> 4;
  const int l15 = l & 15;

  for (int kk = 0; kk < KDIM; kk += 32) {
    __syncthreads();
    async_copy16(A + aoff0 + kk, sA_w);
    async_copy16(A + aoff1 + kk, sA_w + 512);
    async_copy16(B + boff0 + kk, sB_w);
    async_copy16(B + boff1 + kk, sB_w + 512);
    __syncthreads();
    short8 af[4], bfv[4];
    #pragma unroll
    for (int i = 0; i < 4; ++i)
      af[i] = *(const short8*)(sA + (wr + i * 16 + l15) * 32 + quad * 8);
    #pragma unroll
    for (int j = 0; j < 4; ++j)
      bfv[j] = *(const short8*)(sB + (wc + j * 16 + l15) * 32 + quad * 8);
    #pragma unroll
    for (int i = 0; i < 4; ++i)
      #pragma unroll
      for (int j = 0; j < 4; ++j)
        acc[i][j] = __builtin_amdgcn_mfma_f32_16x16x32_bf16(af[i], bfv[j], acc[i][j], 0, 0, 0);
  }

  // epilogue: BN + store. C/D layout: row = quad*4+reg, col = lane&15.
  #pragma unroll
  for (int i = 0; i < 4; ++i) {
    #pragma unroll
    for (int r = 0; r < 4; ++r) {
      const int o = o0 + wr + i * 16 + quad * 4 + r;
      const float s = bn_g[o] * rsqrtf(bn_v[o] + EPS_BN);
      const float tt = bn_b[o] - bn_m[o] * s;
      #pragma unroll
      for (int j = 0; j < 4; ++j) {
        const int n = n0 + wc + j * 16 + l15;
        if (n < NTOK) {
          const float val = acc[i][j][r] * s + tt;
          if (OUTF32)
            ((float*)out)[((size_t)b * DIM + o) * NTOK + n] = val;
          else
            ((ushort_t*)out)[((size_t)b * H_QKV + o) * QSTR + n] = f2bf(val);
        }
      }
    }
  }
}

// ---------------- depthwise conv 3x3 + BN on q ; transpose q,k to (bh,n,32) ----------------
__global__ __launch_bounds__(64) void k_dwq(
    const ushort_t* __restrict__ qkvb, const float* __restrict__ dw_w,
    const float* __restrict__ dg, const float* __restrict__ db,
    const float* __restrict__ dm, const float* __restrict__ dv,
    ushort_t* __restrict__ qt, ushort_t* __restrict__ kt) {
  __shared__ ushort_t sq[32 * QSTR];
  __shared__ ushort_t sk[32 * QSTR];
  const int bh = blockIdx.x;
  const int b = bh >> 3, h = bh & 7;
  const int l = threadIdx.x;
  const int d = l & 31;
  const int half = l >> 5;
  const int c = h * 32 + d;
  float wv[9];
  #pragma unroll
  for (int tp = 0; tp < 9; ++tp) wv[tp] = dw_w[c * 9 + tp];
  const float s = dg[c] * rsqrtf(dv[c] + EPS_BN);
  const float tt = db[c] - dm[c] * s;
  // stage q, k channel tiles: 32 rows x 224 (rows contiguous) = 896 uint4 each
  const uint4* gq = (const uint4*)(qkvb + ((size_t)b * H_QKV + h * 32) * QSTR);
  const uint4* gk = (const uint4*)(qkvb + ((size_t)b * H_QKV + NH_KD + h * 32) * QSTR);
  uint4* lq = (uint4*)sq;
  uint4* lk = (uint4*)sk;
  for (int i = l; i < 896; i += 64) { lq[i] = gq[i]; lk[i] = gk[i]; }
  __syncthreads();
  for (int i = 0; i < 98; ++i) {
    const int n = i * 2 + half;
    const int y = n / 14, x = n - y * 14;
    float a = 0.f;
    #pragma unroll
    for (int dy = -1; dy <= 1; ++dy)
      #pragma unroll
      for (int dx = -1; dx <= 1; ++dx) {
        const int yy = y + dy, xx = x + dx;
        if (yy >= 0 && yy < 14 && xx >= 0 && xx < 14)
          a += bf2f(sq[d * QSTR + yy * 14 + xx]) * wv[(dy + 1) * 3 + (dx + 1)];
      }
    const float outv = (a * s + tt) * SCALE_QK;   // fold qk scale into q
    qt[((size_t)bh * NTOK + n) * 32 + d] = f2bf(outv);
    kt[((size_t)bh * NTOK + n) * 32 + d] = sk[d * QSTR + n];
  }
}

// ---------------- fused attention per (b,h) ----------------
// 256 threads, static LDS = 13312 + 28672 + 16384 = 58368 B (2 blocks/CU).
// V fragments are read directly from global (L2-resident, 16B-aligned via QSTR).
__global__ __launch_bounds__(256, 2) void k_attn(
    const ushort_t* __restrict__ qt, const ushort_t* __restrict__ kt,
    const ushort_t* __restrict__ qkvb, const float* __restrict__ abg,
    ushort_t* __restrict__ rbuf) {
  __shared__ ushort_t sK[208 * 32];        // K rows n-major, rows 196..207 zeroed
  __shared__ ushort_t sP[4 * 16 * 224];    // per-wave attn tile, cols 208..223 zeroed
  __shared__ ushort_t sO[4 * 16 * 128];    // per-wave output transpose tile
  const int bh = blockIdx.x;
  const int b = bh >> 3, h = bh & 7;
  const int t = threadIdx.x;
  const int w = t >> 6, l = t & 63;
  const int quad = l >> 4, l15 = l & 15;

  {
    const uint4* gk = (const uint4*)(kt + (size_t)bh * NTOK * 32);
    uint4* lk = (uint4*)sK;
    for (int i = t; i < 784; i += 256) lk[i] = gk[i];   // 196 rows x 32 = 784 uint4
    const uint4 z = make_uint4(0, 0, 0, 0);
    if (t < 48) lk[784 + t] = z;                        // rows 196..207
    if (t < 128) {                                      // sP pad cols 208..223, all 4 waves
      const int wb = t >> 5, rr = (t >> 1) & 15, hf = t & 1;
      *(uint4*)(sP + wb * 3584 + rr * 224 + 208 + hf * 8) = z;
    }
  }
  __syncthreads();

  const ushort_t* qbase = qt + (size_t)bh * NTOK * 32;
  const ushort_t* vbase = qkvb + ((size_t)b * H_QKV + 2 * NH_KD + h * DD) * QSTR;
  ushort_t* myP = sP + w * (16 * 224);
  ushort_t* myO = sO + w * (16 * 128);
  const floatx4 zero4 = {0.f, 0.f, 0.f, 0.f};

  for (int rt = w; rt < 13; rt += 4) {
    // ---- QK^T: logits 16 x 208, K = 32 exactly
    int qrow = rt * 16 + l15; if (qrow > NTOK - 1) qrow = NTOK - 1;
    const short8 aq = *(const short8*)(qbase + qrow * 32 + quad * 8);
    floatx4 lg[13];
    #pragma unroll
    for (int j = 0; j < 13; ++j) {
      const short8 bk = *(const short8*)(sK + (j * 16 + l15) * 32 + quad * 8);
      lg[j] = __builtin_amdgcn_mfma_f32_16x16x32_bf16(aq, bk, zero4, 0, 0, 0);
    }
    // ---- + bias, mask, softmax (row = quad*4+r, cols on l15 x j)
    float mx[4] = {-3e38f, -3e38f, -3e38f, -3e38f};
    #pragma unroll
    for (int r = 0; r < 4; ++r) {
      int n = rt * 16 + quad * 4 + r; if (n > NTOK - 1) n = NTOK - 1;
      const float* abrow = abg + ((size_t)h * NTOK + n) * NTOK;
      #pragma unroll
      for (int j = 0; j < 13; ++j) {
        const int m = j * 16 + l15;
        float v = lg[j][r];
        v = (m < NTOK) ? (v + abrow[m]) : -1e30f;
        lg[j][r] = v;
        mx[r] = fmaxf(mx[r], v);
      }
    }
    #pragma unroll
    for (int r = 0; r < 4; ++r) {
      float m = mx[r];
      m = fmaxf(m, __shfl_xor(m, 1));
      m = fmaxf(m, __shfl_xor(m, 2));
      m = fmaxf(m, __shfl_xor(m, 4));
      m = fmaxf(m, __shfl_xor(m, 8));
      mx[r] = m;
    }
    float sum[4] = {0.f, 0.f, 0.f, 0.f};
    #pragma unroll
    for (int j = 0; j < 13; ++j)
      #pragma unroll
      for (int r = 0; r < 4; ++r) {
        const float e = __expf(lg[j][r] - mx[r]);
        lg[j][r] = e;
        sum[r] += e;
      }
    #pragma unroll
    for (int r = 0; r < 4; ++r) {
      float sv = sum[r];
      sv += __shfl_xor(sv, 1);
      sv += __shfl_xor(sv, 2);
      sv += __shfl_xor(sv, 4);
      sv += __shfl_xor(sv, 8);
      sum[r] = 1.f / sv;
    }
    #pragma unroll
    for (int j = 0; j < 13; ++j)
      #pragma unroll
      for (int r = 0; r < 4; ++r)
        myP[(quad * 4 + r) * 224 + j * 16 + l15] = f2bf(lg[j][r] * sum[r]);

    // ---- AV: out 16 x 128; attn A-frags from LDS, V B-frags from global
    short8 aA[7];
    #pragma unroll
    for (int ks = 0; ks < 7; ++ks)
      aA[ks] = *(const short8*)(myP + l15 * 224 + ks * 32 + quad * 8);
    #pragma unroll
    for (int ct = 0; ct < 8; ++ct) {
      floatx4 a = zero4;
      #pragma unroll
      for (int ks = 0; ks < 7; ++ks) {
        const short8 bv = *(const short8*)(vbase + (size_t)(ct * 16 + l15) * QSTR + ks * 32 + quad * 8);
        a = __builtin_amdgcn_mfma_f32_16x16x32_bf16(aA[ks], bv, a, 0, 0, 0);
      }
      #pragma unroll
      for (int r = 0; r < 4; ++r) {
        const float v = a[r];
        myO[(quad * 4 + r) * 128 + ct * 16 + l15] = f2bf(v > 0.f ? v : 0.f);
      }
    }
    // ---- wide stores: rbuf (b, n, DHF) bf16
    #pragma unroll
    for (int p = 0; p < 4; ++p) {
      const int nl = p * 4 + quad;
      const int n = rt * 16 + nl;
      const uint4 val = *(const uint4*)(myO + nl * 128 + l15 * 8);
      if (n < NTOK)
        *(uint4*)(rbuf + ((size_t)b * NTOK + n) * DHF + h * DD + l15 * 8) = val;
    }
  }
}

// ---------------- launch ----------------
extern "C" void kernel_launch(void* const* d_in, const int* in_sizes, int n_in,
                              void* d_out, int out_size, void* d_ws, size_t ws_size,
                              hipStream_t stream) {
  const float* x      = (const float*)d_in[0];
  const float* qkv_w  = (const float*)d_in[1];
  const float* qkv_g  = (const float*)d_in[2];
  const float* qkv_b  = (const float*)d_in[3];
  const float* qkv_m  = (const float*)d_in[4];
  const float* qkv_v  = (const float*)d_in[5];
  const float* dw_w   = (const float*)d_in[6];
  const float* dw_g   = (const float*)d_in[7];
  const float* dw_b   = (const float*)d_in[8];
  const float* dw_m   = (const float*)d_in[9];
  const float* dw_v   = (const float*)d_in[10];
  const float* proj_w = (const float*)d_in[11];
  const float* proj_g = (const float*)d_in[12];
  const float* proj_b = (const float*)d_in[13];
  const float* proj_m = (const float*)d_in[14];
  const float* proj_v = (const float*)d_in[15];
  const float* ab     = (const float*)d_in[16];
  const int*   idxs   = (const int*)d_in[17];
  (void)in_sizes; (void)n_in; (void)out_size;

  // fixed buffers (3.2 MB)
  char* p = (char*)d_ws;
  ushort_t* wqkvb  = (ushort_t*)p; p += (size_t)H_QKV * DIM * 2;
  ushort_t* wprojb = (ushort_t*)p; p += (size_t)DIM * DHF * 2;
  float*    abg    = (float*)p;    p += (size_t)HEADS * NTOK * NTOK * 4;
  const size_t fixed = (size_t)(p - (char*)d_ws);
  // per-batch-element footprint: xb + qkvb + qt + kt + rbuf
  const size_t perb = (size_t)NTOK * DIM * 2 + (size_t)H_QKV * QSTR * 2
                    + 2 * (size_t)HEADS * NTOK * 32 * 2 + (size_t)NTOK * DHF * 2;
  int cb = 8;
  const int cands[6] = {256, 128, 64, 32, 16, 8};
  for (int i = 0; i < 6; ++i) {
    if (fixed + (size_t)cands[i] * perb <= ws_size) { cb = cands[i]; break; }
  }
  ushort_t* xb   = (ushort_t*)p;
  ushort_t* qkvb = xb + (size_t)cb * NTOK * DIM;
  ushort_t* qt   = qkvb + (size_t)cb * H_QKV * QSTR;
  ushort_t* kt   = qt + (size_t)cb * HEADS * NTOK * 32;
  ushort_t* rbuf = kt + (size_t)cb * HEADS * NTOK * 32;

  k_prep_w<<<(H_QKV * DIM + DIM * DHF + 255) / 256, 256, 0, stream>>>(qkv_w, proj_w, wqkvb, wprojb);
  k_prep_ab<<<(HEADS * NTOK * NTOK + 255) / 256, 256, 0, stream>>>(ab, idxs, abg);

  for (int b0 = 0; b0 < BATCH; b0 += cb) {
    k_prep_x<<<dim3(6, cb), 256, 0, stream>>>(x + (size_t)b0 * DIM * NTOK, xb);
    k_gemm<DIM, false><<<dim3(24, cb), 256, 0, stream>>>(wqkvb, xb, qkv_g, qkv_b, qkv_m, qkv_v, qkvb);
    k_dwq<<<cb * HEADS, 64, 0, stream>>>(qkvb, dw_w, dw_g, dw_b, dw_m, dw_v, qt, kt);
    k_attn<<<cb * HEADS, 256, 0, stream>>>(qt, kt, qkvb, abg, rbuf);
    k_gemm<DHF, true><<<dim3(6, cb), 256, 0, stream>>>(wprojb, rbuf, proj_g, proj_b, proj_m, proj_v,
                                                       (float*)d_out + (size_t)b0 * DIM * NTOK);
  }
}

// Round 3
// 685.824 us; speedup vs baseline: 1.1596x; 1.1596x over previous
//
#include <hip/hip_runtime.h>
#include <hip/hip_bf16.h>
#include <stdint.h>

// Problem constants
#define DIM 384
#define KEY_DIM 32
#define HEADS 8
#define RES 14
#define NTOK 196
#define NH_KD 256
#define DD 128
#define DHF 1024
#define H_QKV 1536
#define BATCH 256
#define QSTR 224          // padded token stride (per-b), 16B-aligned
#define EPS_BN 1e-5f
#define LOG2E 1.4426950408889634f
#define QSCALE 0.25501860152f   // 32^-0.5 * log2(e)
#define PSTR 232          // LDS stride for P and V tiles (2-way-conflict pattern)

typedef unsigned short ushort_t;
typedef __attribute__((ext_vector_type(8))) short short8;
typedef __attribute__((ext_vector_type(4))) float floatx4;

__device__ __forceinline__ ushort_t f2bf(float f) {
  union { float f; unsigned int u; } v; v.f = f;
  unsigned int u = v.u;
  unsigned int r = (u + 0x7FFFu + ((u >> 16) & 1u)) >> 16;
  return (ushort_t)r;
}
__device__ __forceinline__ float bf2f(ushort_t h) {
  union { unsigned int u; float f; } v; v.u = ((unsigned int)h) << 16;
  return v.f;
}
__device__ __forceinline__ void async_copy16(const ushort_t* g, ushort_t* l) {
  __builtin_amdgcn_global_load_lds((const __attribute__((address_space(1))) void*)g,
                                   (__attribute__((address_space(3))) void*)l, 16, 0, 0);
}

// ---------------- prep ----------------
// x (b, c, 196) fp32 -> xb (b, 224, c) bf16, pad rows 196..223 zeroed
__global__ void k_prep_x(const float* __restrict__ x, ushort_t* __restrict__ xb) {
  __shared__ float tile[64][65];
  const int b = blockIdx.y;
  const int c0 = blockIdx.x * 64;
  const int t = threadIdx.x;
  const int tr = t >> 6;
  const int tc = t & 63;
  for (int n0 = 0; n0 < QSTR; n0 += 64) {
    __syncthreads();
    #pragma unroll
    for (int k = 0; k < 16; ++k) {
      int r = k * 4 + tr;
      int n = n0 + tc;
      tile[r][tc] = (n < NTOK) ? x[((size_t)b * DIM + c0 + r) * NTOK + n] : 0.f;
    }
    __syncthreads();
    #pragma unroll
    for (int k = 0; k < 16; ++k) {
      int nl = k * 4 + tr;
      int n = n0 + nl;
      if (n < QSTR) xb[((size_t)b * QSTR + n) * DIM + c0 + tc] = f2bf(tile[tc][nl]);
    }
  }
}

__global__ void k_prep_w(const float* __restrict__ qkv_w, const float* __restrict__ proj_w,
                         ushort_t* __restrict__ wqkvb, ushort_t* __restrict__ wprojb) {
  int i = blockIdx.x * 256 + threadIdx.x;
  const int nA = H_QKV * DIM;
  const int nB = DIM * DHF;
  if (i < nA) wqkvb[i] = f2bf(qkv_w[i]);
  else if (i < nA + nB) wprojb[i - nA] = f2bf(proj_w[i - nA]);
}

// bias table in MFMA C-fragment layout, pre-scaled by log2e, -1e30 in masked cols.
// abgC[(((h*13+rt)*13+j)*64 + lane)*4 + r] -> element (n = rt*16+quad*4+r, m = j*16+l15)
__global__ void k_prep_abC(const float* __restrict__ biases, const int* __restrict__ idxs,
                           float* __restrict__ abgC) {
  int tid = blockIdx.x * 256 + threadIdx.x;
  if (tid >= HEADS * 13 * 13 * 64) return;
  const int l = tid & 63;
  int rem = tid >> 6;
  const int j = rem % 13; rem /= 13;
  const int rt = rem % 13;
  const int h = rem / 13;
  const int quad = l >> 4, l15 = l & 15;
  const int m = j * 16 + l15;
  #pragma unroll
  for (int r = 0; r < 4; ++r) {
    int n = rt * 16 + quad * 4 + r; if (n > NTOK - 1) n = NTOK - 1;
    float v = (m < NTOK) ? biases[h * NTOK + idxs[n * NTOK + m]] * LOG2E : -1e30f;
    abgC[(size_t)tid * 4 + r] = v;
  }
}

// ---------------- flat GEMM: C(M x cb*224) = A(M x K) * B(cb*224 x K)^T + BN ----------------
// grid: (NT, MT). All tiles fully dense (no clamps in K-loop).
template<int KDIM, bool OUTF32>
__global__ __launch_bounds__(256, 2) void k_gemm(
    const ushort_t* __restrict__ A, const ushort_t* __restrict__ B,
    const float* __restrict__ bn_g, const float* __restrict__ bn_b,
    const float* __restrict__ bn_m, const float* __restrict__ bn_v,
    void* __restrict__ out) {
  __shared__ ushort_t sA[128 * 32];
  __shared__ ushort_t sB[128 * 32];
  const int n0 = blockIdx.x * 128;
  const int o0 = blockIdx.y * 128;
  const int t = threadIdx.x;
  const int w = t >> 6;
  const int l = t & 63;
  const int lr = l >> 2;
  const int ls = l & 3;
  const int arow0 = w * 32 + lr;
  const size_t aoff0 = (size_t)(o0 + arow0) * KDIM + ls * 8;
  const size_t aoff1 = aoff0 + (size_t)16 * KDIM;
  const size_t boff0 = (size_t)(n0 + arow0) * KDIM + ls * 8;
  const size_t boff1 = boff0 + (size_t)16 * KDIM;
  ushort_t* sA_w = sA + w * 1024;
  ushort_t* sB_w = sB + w * 1024;

  floatx4 acc[4][4];
  const floatx4 zero4 = {0.f, 0.f, 0.f, 0.f};
  #pragma unroll
  for (int i = 0; i < 4; ++i)
    #pragma unroll
    for (int j = 0; j < 4; ++j) acc[i][j] = zero4;

  const int wr = (w >> 1) * 64;
  const int wc = (w & 1) * 64;
  const int quad = l >> 4;
  const int l15 = l & 15;

  for (int kk = 0; kk < KDIM; kk += 32) {
    __syncthreads();
    async_copy16(A + aoff0 + kk, sA_w);
    async_copy16(A + aoff1 + kk, sA_w + 512);
    async_copy16(B + boff0 + kk, sB_w);
    async_copy16(B + boff1 + kk, sB_w + 512);
    __syncthreads();
    short8 af[4], bfv[4];
    #pragma unroll
    for (int i = 0; i < 4; ++i)
      af[i] = *(const short8*)(sA + (wr + i * 16 + l15) * 32 + quad * 8);
    #pragma unroll
    for (int j = 0; j < 4; ++j)
      bfv[j] = *(const short8*)(sB + (wc + j * 16 + l15) * 32 + quad * 8);
    #pragma unroll
    for (int i = 0; i < 4; ++i)
      #pragma unroll
      for (int j = 0; j < 4; ++j)
        acc[i][j] = __builtin_amdgcn_mfma_f32_16x16x32_bf16(af[i], bfv[j], acc[i][j], 0, 0, 0);
  }

  // epilogue: decode gn -> (b, nn), BN, store. C/D: row=quad*4+r, col=lane&15.
  unsigned bq[4], nn[4];
  #pragma unroll
  for (int j = 0; j < 4; ++j) {
    const unsigned gn = n0 + wc + j * 16 + l15;
    bq[j] = gn / QSTR;
    nn[j] = gn - bq[j] * QSTR;
  }
  #pragma unroll
  for (int i = 0; i < 4; ++i) {
    #pragma unroll
    for (int r = 0; r < 4; ++r) {
      const int o = o0 + wr + i * 16 + quad * 4 + r;
      const float s = bn_g[o] * rsqrtf(bn_v[o] + EPS_BN);
      const float tt = bn_b[o] - bn_m[o] * s;
      #pragma unroll
      for (int j = 0; j < 4; ++j) {
        const float val = acc[i][j][r] * s + tt;
        if (OUTF32) {
          if (nn[j] < NTOK)
            ((float*)out)[((size_t)bq[j] * DIM + o) * NTOK + nn[j]] = val;
        } else {
          ((ushort_t*)out)[((size_t)bq[j] * H_QKV + o) * QSTR + nn[j]] = f2bf(val);
        }
      }
    }
  }
}

// ---------------- depthwise conv 3x3 + BN on q ; transpose q,k to (bh,n,32) ----------------
__global__ __launch_bounds__(64) void k_dwq(
    const ushort_t* __restrict__ qkvb, const float* __restrict__ dw_w,
    const float* __restrict__ dg, const float* __restrict__ db,
    const float* __restrict__ dm, const float* __restrict__ dv,
    ushort_t* __restrict__ qt, ushort_t* __restrict__ kt) {
  __shared__ ushort_t sq[32 * QSTR];
  __shared__ ushort_t sk[32 * QSTR];
  const int bh = blockIdx.x;
  const int b = bh >> 3, h = bh & 7;
  const int l = threadIdx.x;
  const int d = l & 31;
  const int half = l >> 5;
  const int c = h * 32 + d;
  float wv[9];
  #pragma unroll
  for (int tp = 0; tp < 9; ++tp) wv[tp] = dw_w[c * 9 + tp];
  const float s = dg[c] * rsqrtf(dv[c] + EPS_BN);
  const float tt = db[c] - dm[c] * s;
  const uint4* gq = (const uint4*)(qkvb + ((size_t)b * H_QKV + h * 32) * QSTR);
  const uint4* gk = (const uint4*)(qkvb + ((size_t)b * H_QKV + NH_KD + h * 32) * QSTR);
  uint4* lq = (uint4*)sq;
  uint4* lk = (uint4*)sk;
  for (int i = l; i < 896; i += 64) { lq[i] = gq[i]; lk[i] = gk[i]; }
  __syncthreads();
  for (int i = 0; i < 98; ++i) {
    const int n = i * 2 + half;
    const int y = n / 14, x = n - y * 14;
    float a = 0.f;
    #pragma unroll
    for (int dy = -1; dy <= 1; ++dy)
      #pragma unroll
      for (int dx = -1; dx <= 1; ++dx) {
        const int yy = y + dy, xx = x + dx;
        if (yy >= 0 && yy < 14 && xx >= 0 && xx < 14)
          a += bf2f(sq[d * QSTR + yy * 14 + xx]) * wv[(dy + 1) * 3 + (dx + 1)];
      }
    const float outv = (a * s + tt) * QSCALE;   // fold qk scale + log2e into q
    qt[((size_t)bh * NTOK + n) * 32 + d] = f2bf(outv);
    kt[((size_t)bh * NTOK + n) * 32 + d] = sk[d * QSTR + n];
  }
}

// ---------------- fused attention, d-split: 2 blocks per (b,h), 64 V-channels each ------
// 256 thr; LDS: sV 64x232 + sP 4x16x232 (bf16) = 59392 B -> 2 blocks/CU.
// K fragments live in registers (loaded once, coalesced). Bias enters as MFMA C-init.
__global__ __launch_bounds__(256, 2) void k_attn(
    const ushort_t* __restrict__ qt, const ushort_t* __restrict__ kt,
    const ushort_t* __restrict__ qkvb, const float* __restrict__ abgC,
    ushort_t* __restrict__ rbuf) {
  __shared__ ushort_t sV[64 * PSTR];
  __shared__ ushort_t sP[4 * 16 * PSTR];
  const int id = blockIdx.x;
  const int dhalf = id & 1;
  const int bh = id >> 1;
  const int b = bh >> 3, h = bh & 7;
  const int t = threadIdx.x;
  const int w = t >> 6, l = t & 63;
  const int quad = l >> 4, l15 = l & 15;

  // stage V half (64 rows x 196 cols, padded stride): coalesced 448B rows
  {
    const ushort_t* vsrc = qkvb + ((size_t)b * H_QKV + 2 * NH_KD + h * DD + dhalf * 64) * QSTR;
    for (int i = t; i < 2048; i += 256) {
      const int row = i >> 5, col = i & 31;
      if (col < 28)
        *(uint4*)(sV + row * PSTR + col * 8) = *(const uint4*)(vsrc + (size_t)row * QSTR + col * 8);
    }
    if (t < 128) {   // zero sP pad cols 208..223 for all 4 waves
      const int wb = t >> 5, rr = (t >> 1) & 15, hf = t & 1;
      *(uint4*)(sP + wb * 16 * PSTR + rr * PSTR + 208 + hf * 8) = make_uint4(0, 0, 0, 0);
    }
  }
  // K fragments -> registers (same for every wave/rt); clamp rows >=196 (bias masks them)
  short8 kf[13];
  const ushort_t* kbase = kt + (size_t)bh * NTOK * 32;
  #pragma unroll
  for (int j = 0; j < 13; ++j) {
    int krow = j * 16 + l15; if (krow > NTOK - 1) krow = NTOK - 1;
    kf[j] = *(const short8*)(kbase + krow * 32 + quad * 8);
  }
  __syncthreads();

  const ushort_t* qbase = qt + (size_t)bh * NTOK * 32;
  ushort_t* myP = sP + w * 16 * PSTR;
  const floatx4 zero4 = {0.f, 0.f, 0.f, 0.f};

  for (int rt = w; rt < 13; rt += 4) {
    int qrow = rt * 16 + l15; if (qrow > NTOK - 1) qrow = NTOK - 1;
    const short8 aq = *(const short8*)(qbase + qrow * 32 + quad * 8);
    const floatx4* cb = (const floatx4*)(abgC) + ((size_t)(h * 13 + rt) * 13) * 64 + l;
    floatx4 lg[13];
    #pragma unroll
    for (int j = 0; j < 13; ++j)
      lg[j] = __builtin_amdgcn_mfma_f32_16x16x32_bf16(aq, kf[j], cb[j * 64], 0, 0, 0);

    // softmax in log2 domain (scales pre-folded)
    float mx[4] = {-3e38f, -3e38f, -3e38f, -3e38f};
    #pragma unroll
    for (int j = 0; j < 13; ++j)
      #pragma unroll
      for (int r = 0; r < 4; ++r) mx[r] = fmaxf(mx[r], lg[j][r]);
    #pragma unroll
    for (int r = 0; r < 4; ++r) {
      float m = mx[r];
      m = fmaxf(m, __shfl_xor(m, 1));
      m = fmaxf(m, __shfl_xor(m, 2));
      m = fmaxf(m, __shfl_xor(m, 4));
      m = fmaxf(m, __shfl_xor(m, 8));
      mx[r] = m;
    }
    float sum[4] = {0.f, 0.f, 0.f, 0.f};
    #pragma unroll
    for (int j = 0; j < 13; ++j)
      #pragma unroll
      for (int r = 0; r < 4; ++r) {
        const float e = exp2f(lg[j][r] - mx[r]);
        lg[j][r] = e;
        sum[r] += e;
      }
    #pragma unroll
    for (int r = 0; r < 4; ++r) {
      float sv = sum[r];
      sv += __shfl_xor(sv, 1);
      sv += __shfl_xor(sv, 2);
      sv += __shfl_xor(sv, 4);
      sv += __shfl_xor(sv, 8);
      sum[r] = 1.f / sv;
    }
    #pragma unroll
    for (int j = 0; j < 13; ++j)
      #pragma unroll
      for (int r = 0; r < 4; ++r)
        myP[(quad * 4 + r) * PSTR + j * 16 + l15] = f2bf(lg[j][r] * sum[r]);

    // AV: out 16 x 64 (this block's half); A-frags from LDS, V from LDS
    short8 aA[7];
    #pragma unroll
    for (int ks = 0; ks < 7; ++ks)
      aA[ks] = *(const short8*)(myP + l15 * PSTR + ks * 32 + quad * 8);
    #pragma unroll
    for (int ct = 0; ct < 4; ++ct) {
      floatx4 a = zero4;
      #pragma unroll
      for (int ks = 0; ks < 7; ++ks) {
        const short8 bv = *(const short8*)(sV + (ct * 16 + l15) * PSTR + ks * 32 + quad * 8);
        a = __builtin_amdgcn_mfma_f32_16x16x32_bf16(aA[ks], bv, a, 0, 0, 0);
      }
      #pragma unroll
      for (int r = 0; r < 4; ++r) {
        const float v = a[r];
        myP[(quad * 4 + r) * PSTR + ct * 16 + l15] = f2bf(v > 0.f ? v : 0.f);  // reuse as O^T
      }
    }
    // wide stores: rbuf (b, n224, DHF) bf16, 8B per lane
    #pragma unroll
    for (int p = 0; p < 4; ++p) {
      const int nl = p * 4 + quad;
      const int n = rt * 16 + nl;
      if (n < NTOK) {
        const uint2 val = *(const uint2*)(myP + nl * PSTR + l15 * 4);
        *(uint2*)(rbuf + ((size_t)b * QSTR + n) * DHF + h * DD + dhalf * 64 + l15 * 4) = val;
      }
    }
  }
}

// ---------------- launch ----------------
extern "C" void kernel_launch(void* const* d_in, const int* in_sizes, int n_in,
                              void* d_out, int out_size, void* d_ws, size_t ws_size,
                              hipStream_t stream) {
  const float* x      = (const float*)d_in[0];
  const float* qkv_w  = (const float*)d_in[1];
  const float* qkv_g  = (const float*)d_in[2];
  const float* qkv_b  = (const float*)d_in[3];
  const float* qkv_m  = (const float*)d_in[4];
  const float* qkv_v  = (const float*)d_in[5];
  const float* dw_w   = (const float*)d_in[6];
  const float* dw_g   = (const float*)d_in[7];
  const float* dw_b   = (const float*)d_in[8];
  const float* dw_m   = (const float*)d_in[9];
  const float* dw_v   = (const float*)d_in[10];
  const float* proj_w = (const float*)d_in[11];
  const float* proj_g = (const float*)d_in[12];
  const float* proj_b = (const float*)d_in[13];
  const float* proj_m = (const float*)d_in[14];
  const float* proj_v = (const float*)d_in[15];
  const float* ab     = (const float*)d_in[16];
  const int*   idxs   = (const int*)d_in[17];
  (void)in_sizes; (void)n_in; (void)out_size;

  char* p = (char*)d_ws;
  ushort_t* wqkvb  = (ushort_t*)p; p += (size_t)H_QKV * DIM * 2;
  ushort_t* wprojb = (ushort_t*)p; p += (size_t)DIM * DHF * 2;
  float*    abgC   = (float*)p;    p += (size_t)HEADS * 13 * 13 * 64 * 4 * 4;
  const size_t fixed = (size_t)(p - (char*)d_ws);
  const size_t perb = (size_t)QSTR * DIM * 2 + (size_t)H_QKV * QSTR * 2
                    + 2 * (size_t)HEADS * NTOK * 32 * 2 + (size_t)QSTR * DHF * 2;
  int cb = 8;
  const int cands[6] = {256, 128, 64, 32, 16, 8};
  for (int i = 0; i < 6; ++i) {
    if (fixed + (size_t)cands[i] * perb <= ws_size) { cb = cands[i]; break; }
  }
  ushort_t* xb   = (ushort_t*)p;
  ushort_t* qkvb = xb + (size_t)cb * QSTR * DIM;
  ushort_t* qt   = qkvb + (size_t)cb * H_QKV * QSTR;
  ushort_t* kt   = qt + (size_t)cb * HEADS * NTOK * 32;
  ushort_t* rbuf = kt + (size_t)cb * HEADS * NTOK * 32;

  k_prep_w<<<(H_QKV * DIM + DIM * DHF + 255) / 256, 256, 0, stream>>>(qkv_w, proj_w, wqkvb, wprojb);
  k_prep_abC<<<(HEADS * 13 * 13 * 64 + 255) / 256, 256, 0, stream>>>(ab, idxs, abgC);

  const int NT = cb * QSTR / 128;   // dense flat column tiles
  for (int b0 = 0; b0 < BATCH; b0 += cb) {
    k_prep_x<<<dim3(6, cb), 256, 0, stream>>>(x + (size_t)b0 * DIM * NTOK, xb);
    k_gemm<DIM, false><<<dim3(NT, 12), 256, 0, stream>>>(wqkvb, xb, qkv_g, qkv_b, qkv_m, qkv_v, qkvb);
    k_dwq<<<cb * HEADS, 64, 0, stream>>>(qkvb, dw_w, dw_g, dw_b, dw_m, dw_v, qt, kt);
    k_attn<<<cb * HEADS * 2, 256, 0, stream>>>(qt, kt, qkvb, abgC, rbuf);
    k_gemm<DHF, true><<<dim3(NT, 3), 256, 0, stream>>>(wprojb, rbuf, proj_g, proj_b, proj_m, proj_v,
                                                       (float*)d_out + (size_t)b0 * DIM * NTOK);
  }
}